// Round 9
// baseline (1173.776 us; speedup 1.0000x reference)
//
#include <hip/hip_runtime.h>

typedef unsigned short u16;
typedef unsigned int   u32;
typedef unsigned long long u64;
typedef __attribute__((ext_vector_type(8))) short bf16x8;
typedef __attribute__((ext_vector_type(4))) float f32x4;

#define GK 768            // K dim of all GEMMs
#define NSTEP 196
#define HSTEP 49152       // 64*768 elements per step slab
#define PWG 24            // workgroups per batch-group
#define NGRP 8            // batch groups (8 batches each)
#define NBLK 256          // launched workgroups (claim protocol)
#define FLINE 32          // ints per 128B flag line
#define FLAG0 64          // fast flags: one line per producer WG (192 lines)
#define MIR0 6656         // agent mirror flags: one line per group (8 lines)
#define GUARD (1 << 18)   // spin guard: force-exit instead of hanging

__device__ __forceinline__ u16 f2bf(float f) {
    u32 u = __float_as_uint(f);
    u = (u + 0x7fffu + ((u >> 16) & 1u)) >> 16;
    return (u16)u;
}
__device__ __forceinline__ float bf2f(u16 h) { return __uint_as_float(((u32)h) << 16); }

__device__ __forceinline__ int agent_load(const int* p) {
    return __hip_atomic_load(p, __ATOMIC_RELAXED, __HIP_MEMORY_SCOPE_AGENT);
}
__device__ __forceinline__ void agent_store(int* p, int v) {
    __hip_atomic_store(p, v, __ATOMIC_RELAXED, __HIP_MEMORY_SCOPE_AGENT);
}
// THE round-9 primitive: read a flag via atomic-add-0. Vector atomics execute
// at the TCC (L2) and are never served from L1 -- the repeated-read staleness
// that broke sc0 polling (R4/R5/R6) cannot occur. sc0 = return-old.
__device__ __forceinline__ int atomic_read_l2(int* p) {
    int v; int zero = 0;
    asm volatile("global_atomic_add %0, %1, %2, off sc0\n\t"
                 "s_waitcnt vmcnt(0)"
                 : "=&v"(v) : "v"(p), "v"(zero) : "memory");
    return v;
}

// ---------------------------------------------------------------------------
// fp32 -> bf16 convert for x, Wx, Wp; blocks 0..31 zero the 8192 flag ints.
// ---------------------------------------------------------------------------
__global__ __launch_bounds__(256) void cvt_kernel(
    const float4* __restrict__ x, const float4* __restrict__ wx,
    const float4* __restrict__ wp,
    u32* __restrict__ xb, u32* __restrict__ wxb, u32* __restrict__ wpb,
    int* __restrict__ flags)
{
    const int N1 = 9633792 / 4, N2 = 1769472 / 4;
    int i = blockIdx.x * 256 + threadIdx.x;
    if (blockIdx.x < 32) flags[blockIdx.x * 256 + threadIdx.x] = 0;
    const float4* src; u32* dst; int off;
    if (i < N1)            { src = x;  dst = xb;  off = i; }
    else if (i < N1 + N2)  { src = wx; dst = wxb; off = i - N1; }
    else                   { src = wp; dst = wpb; off = i - N1 - N2; }
    float4 v = src[off];
    u32 lo = (u32)f2bf(v.x) | ((u32)f2bf(v.y) << 16);
    u32 hi = (u32)f2bf(v.z) | ((u32)f2bf(v.w) << 16);
    dst[(size_t)off * 2]     = lo;
    dst[(size_t)off * 2 + 1] = hi;
}

// ---------------------------------------------------------------------------
// GEMM: out[M][N] = A[M][K] @ B[N][K]^T   (A,B bf16 row-major K-contiguous)
// MODE 1: += bias[col], bf16 out remapped to [n][b][col] with m = b*196+n
// MODE 0: fp32 out; A rows are m = n*64+b, output row remapped to b*196+n
// ---------------------------------------------------------------------------
template<int MODE>
__global__ __launch_bounds__(256) void gemm_bt(
    const u16* __restrict__ A, const u16* __restrict__ B,
    const float* __restrict__ bias, void* __restrict__ outv)
{
    __shared__ u16 As[128 * 40];
    __shared__ u16 Bs[128 * 40];
    const int tid  = threadIdx.x;
    const int lane = tid & 63;
    const int wv   = tid >> 6;
    const int m0 = blockIdx.y * 128;
    const int n0 = blockIdx.x * 128;
    const int wm = (wv & 1) * 64;
    const int wn = (wv >> 1) * 64;

    f32x4 acc[4][4];
#pragma unroll
    for (int i = 0; i < 4; ++i)
#pragma unroll
        for (int j = 0; j < 4; ++j) acc[i][j] = (f32x4){0.f, 0.f, 0.f, 0.f};

    const int r0 = tid >> 2, q0 = tid & 3;
    const u16* gA0 = A + (size_t)(m0 + r0)      * GK + q0 * 8;
    const u16* gA1 = A + (size_t)(m0 + r0 + 64) * GK + q0 * 8;
    const u16* gB0 = B + (size_t)(n0 + r0)      * GK + q0 * 8;
    const u16* gB1 = B + (size_t)(n0 + r0 + 64) * GK + q0 * 8;
    u16* sA0 = As + r0 * 40 + q0 * 8;
    u16* sA1 = As + (r0 + 64) * 40 + q0 * 8;
    u16* sB0 = Bs + r0 * 40 + q0 * 8;
    u16* sB1 = Bs + (r0 + 64) * 40 + q0 * 8;

    const int fr = lane & 15, fq = lane >> 4;
    const u16* fA = As + (wm + fr) * 40 + fq * 8;
    const u16* fB = Bs + (wn + fr) * 40 + fq * 8;

    for (int kt = 0; kt < GK / 32; ++kt) {
        uint4 a0 = *(const uint4*)(gA0 + kt * 32);
        uint4 a1 = *(const uint4*)(gA1 + kt * 32);
        uint4 b0 = *(const uint4*)(gB0 + kt * 32);
        uint4 b1 = *(const uint4*)(gB1 + kt * 32);
        __syncthreads();
        *(uint4*)sA0 = a0; *(uint4*)sA1 = a1;
        *(uint4*)sB0 = b0; *(uint4*)sB1 = b1;
        __syncthreads();
        bf16x8 af[4], bfr[4];
#pragma unroll
        for (int mi = 0; mi < 4; ++mi) af[mi]  = *(const bf16x8*)(fA + mi * 16 * 40);
#pragma unroll
        for (int ni = 0; ni < 4; ++ni) bfr[ni] = *(const bf16x8*)(fB + ni * 16 * 40);
#pragma unroll
        for (int mi = 0; mi < 4; ++mi)
#pragma unroll
            for (int ni = 0; ni < 4; ++ni)
                acc[mi][ni] = __builtin_amdgcn_mfma_f32_16x16x32_bf16(
                    af[mi], bfr[ni], acc[mi][ni], 0, 0, 0);
    }

    if (MODE == 1) {
        u16* out = (u16*)outv;
#pragma unroll
        for (int mi = 0; mi < 4; ++mi) {
#pragma unroll
            for (int ni = 0; ni < 4; ++ni) {
                int col = n0 + wn + ni * 16 + fr;
                float bv = bias[col];
#pragma unroll
                for (int r = 0; r < 4; ++r) {
                    int m = m0 + wm + mi * 16 + fq * 4 + r;
                    int b = m / 196;
                    int nn = m - b * 196;
                    u16 hv = f2bf(acc[mi][ni][r] + bv);
                    int other = __shfl_xor((int)hv, 1, 64);
                    if (!(lane & 1)) {
                        u32 packed = (u32)hv | (((u32)(u16)other) << 16);
                        size_t eidx = ((size_t)nn * 64 + (size_t)b) * 2304 + (size_t)col;
                        *((u32*)out + (eidx >> 1)) = packed;
                    }
                }
            }
        }
    } else {
        float* out = (float*)outv;
#pragma unroll
        for (int mi = 0; mi < 4; ++mi) {
#pragma unroll
            for (int ni = 0; ni < 4; ++ni) {
                int col = n0 + wn + ni * 16 + fr;
#pragma unroll
                for (int r = 0; r < 4; ++r) {
                    int m = m0 + wm + mi * 16 + fq * 4 + r;   // m = n*64 + b
                    int b = m & 63;
                    int nn = m >> 6;
                    out[((size_t)b * 196 + nn) * 768 + col] = acc[mi][ni][r];
                }
            }
        }
    }
}

// ---------------------------------------------------------------------------
// Batch-split GRU recurrence. Group g owns batches [g*8, g*8+8); 24 WGs x 32
// h-channels; Wh slice in registers; 6 waves = 3 gates x 2 K-halves.
// h exchange: DUAL store (plain -> local L2 [R2/R4/R5-proven fast path] +
// agent -> LLC [keeps rescue mode correct]); consumers use plain loads
// (write-once/read-once addresses, entry acquire fence kills cross-replay
// staleness -- FETCH evidence R5 vs R8 validates the whole scheme).
// Flag detect: wave 5 single-poller; FAST mode polls per-producer flag lines
// via atomic_read_l2 (TCC-executed, L1-immune); bounded spin then sticky
// rescue to agent mirrors. All spins guarded -- cannot hang the container.
// ---------------------------------------------------------------------------
template<bool FAST>
__device__ void recur_core(
    int g, int s, int tid,
    const u16* __restrict__ xz, const float* __restrict__ Wh,
    const float* __restrict__ bh, u16* __restrict__ hsx, int* flags,
    float* hzs)
{
    const int lane = tid & 63;
    const int wv   = tid >> 6;          // 0..5
    const int kh   = wv & 1;            // K half (384 each)
    const int np   = wv >> 1;           // gate index 0..2
    const int fr   = lane & 15, fq = lane >> 4;
    const int c0   = s * 32;            // this WG's h-channel base
    const int B0   = g * 8;             // this group's batch base

    // ---- one-time: Wh slice -> B-frags in registers (bf16) ----
    bf16x8 bfrag[2][12];
#pragma unroll
    for (int j = 0; j < 2; ++j) {
        int row = np * 768 + c0 + j * 16 + fr;
        const float* wp = Wh + (size_t)row * 768 + kh * 384 + fq * 8;
#pragma unroll
        for (int kk = 0; kk < 12; ++kk) {
            float4 f0 = *(const float4*)(wp + kk * 32);
            float4 f1 = *(const float4*)(wp + kk * 32 + 4);
            bf16x8 b;
            b[0] = (short)f2bf(f0.x); b[1] = (short)f2bf(f0.y);
            b[2] = (short)f2bf(f0.z); b[3] = (short)f2bf(f0.w);
            b[4] = (short)f2bf(f1.x); b[5] = (short)f2bf(f1.y);
            b[6] = (short)f2bf(f1.z); b[7] = (short)f2bf(f1.w);
            bfrag[j][kk] = b;
        }
    }

    // gate-phase constants: thread t<256 -> (batch gb, channel gi)
    const int gb = tid >> 5, gi = tid & 31;
    const int gc = c0 + gi;
    float bh0 = 0.f, bh1 = 0.f, bh2 = 0.f, hold = 0.f;
    if (tid < 256) { bh0 = bh[gc]; bh1 = bh[768 + gc]; bh2 = bh[1536 + gc]; }

    // flags: fast = one 128B line per producer (lane l polls producer l%24,
    // 24 distinct lines -> parallel TCC channels); mirror = one line/group.
    const int pl = lane % PWG;
    int* const myflag = &flags[FLAG0 + (g * PWG + s)  * FLINE];
    int* const pollp  = &flags[FLAG0 + (g * PWG + pl) * FLINE];
    int* const mymir  = &flags[MIR0 + g * FLINE + s];
    const int* const pollm = &flags[MIR0 + g * FLINE + pl];

    // preload xz for step 0
    float xgn0 = 0.f, xgn1 = 0.f, xgn2 = 0.f;
    if (tid < 256) {
        size_t xoff = (size_t)(B0 + gb) * 2304 + gc;
        xgn0 = bf2f(xz[xoff]);
        xgn1 = bf2f(xz[xoff + 768]);
        xgn2 = bf2f(xz[xoff + 1536]);
    }

    bool slow = !FAST;

    for (int n = 0; n < NSTEP; ++n) {
        const float xg0 = xgn0, xg1 = xgn1, xg2 = xgn2;   // prefetched

        f32x4 acc0 = (f32x4){0.f, 0.f, 0.f, 0.f};
        f32x4 acc1 = (f32x4){0.f, 0.f, 0.f, 0.f};

        if (n > 0) {
            // wave 5 (no xz loads outstanding) detects; others park at barrier
            if (tid >= 320) {
                bool done = false;
                if (FAST && !slow) {
                    int tries = 0;
                    for (;;) {
                        int v = atomic_read_l2(pollp);
                        if (__all(v >= n)) { done = true; break; }
                        if (++tries > 4096) { slow = true; break; }
                        __builtin_amdgcn_s_sleep(1);
                    }
                }
                if (!done) {
                    int guard = 0;
                    for (;;) {
                        int v = agent_load(pollm);
                        if (__all(v >= n)) break;
                        if (++guard > GUARD) break;   // hang insurance
                        __builtin_amdgcn_s_sleep(1);
                    }
                }
            }
            __syncthreads();

            // A-frags: h[n-1][B0+fr][k]; rows fr>=8 zero (M=8 padded to 16)
            const u16* ap = hsx + (size_t)(n - 1) * HSTEP
                                + (size_t)(B0 + fr) * 768 + kh * 384 + fq * 8;
            const bool arow = fr < 8;
#pragma unroll
            for (int kk = 0; kk < 12; ++kk) {
                bf16x8 a = arow ? *(const bf16x8*)(ap + kk * 32)
                                : (bf16x8){0, 0, 0, 0, 0, 0, 0, 0};
                acc0 = __builtin_amdgcn_mfma_f32_16x16x32_bf16(a, bfrag[0][kk], acc0, 0, 0, 0);
                acc1 = __builtin_amdgcn_mfma_f32_16x16x32_bf16(a, bfrag[1][kk], acc1, 0, 0, 0);
            }
        }

        // partial h_zrn (per K-half) -> LDS
#pragma unroll
        for (int r = 0; r < 4; ++r) {
            int b = fq * 4 + r;
            if (b < 8) {
                hzs[(kh * 8 + b) * 96 + np * 32 + fr]      = acc0[r];
                hzs[(kh * 8 + b) * 96 + np * 32 + 16 + fr] = acc1[r];
            }
        }
        __syncthreads();

        if (tid < 256) {
            float h0 = hzs[gb * 96 + gi]      + hzs[(8 + gb) * 96 + gi]      + bh0;
            float h1 = hzs[gb * 96 + 32 + gi] + hzs[(8 + gb) * 96 + 32 + gi] + bh1;
            float h2 = hzs[gb * 96 + 64 + gi] + hzs[(8 + gb) * 96 + 64 + gi] + bh2;
            float z   = 1.f / (1.f + __expf(-(xg0 + h0)));
            float rr2 = 1.f / (1.f + __expf(-(xg1 + h1)));
            float pre = xg2 + rr2 * h2;
            float e2  = __expf(-2.f * pre);
            float nc  = (1.f - e2) / (1.f + e2);
            float hnew = (1.f - z) * nc + z * hold;
            hold = hnew;

            // pack 4 channels -> 8B; DUAL store: plain (local L2) + agent (LLC)
            u16 hv = f2bf(hnew);
            u32 other = ((u32)__shfl_xor((int)hv, 1, 64)) & 0xffffu;
            u32 v01 = (u32)hv | (other << 16);
            u32 v23 = (u32)__shfl_xor((int)v01, 2, 64);
            if ((tid & 3) == 0) {
                u64 q = (u64)v01 | ((u64)v23 << 32);
                size_t ofs = (size_t)n * HSTEP + (size_t)(B0 + gb) * 768 + gc;
                u64* p = (u64*)(hsx + ofs);
                *p = q;                                              // L2
                __hip_atomic_store(p, q, __ATOMIC_RELAXED,
                                   __HIP_MEMORY_SCOPE_AGENT);        // LLC
            }
        }
        // drain h-stores (no loads outstanding), then publish both flags
        asm volatile("s_waitcnt vmcnt(0)" ::: "memory");
        __syncthreads();
        if (tid == 0)       *myflag = n + 1;           // plain -> local L2
        else if (tid == 64) agent_store(mymir, n + 1); // mirror -> LLC

        // prefetch next step's xz AFTER the publish (latency overlaps poll)
        if (tid < 256) {
            int np1 = (n + 1 < NSTEP) ? n + 1 : NSTEP - 1;
            size_t xoff = ((size_t)np1 * 64 + (B0 + gb)) * 2304 + gc;
            xgn0 = bf2f(xz[xoff]);
            xgn1 = bf2f(xz[xoff + 768]);
            xgn2 = bf2f(xz[xoff + 1536]);
        }
    }
}

// ---------------------------------------------------------------------------
// Persistent cooperative kernel: XCD claim (R5-proven; FETCH=66MB runs prove
// the claimed groups were physically XCD-local) -> placement-adaptive group
// formation -> dispatch. flags: [0..7] claim counters, [15] barrier,
// [FLAG0..] fast lines, [MIR0..] mirrors.
// ---------------------------------------------------------------------------
__global__ __launch_bounds__(384) void recur4_kernel(
    const u16* __restrict__ xz, const float* __restrict__ Wh,
    const float* __restrict__ bh, u16* __restrict__ hsx, int* flags)
{
    __shared__ float hzs[2 * 8 * 96];
    __shared__ int sh_mode, sh_g, sh_s;
    const int tid = threadIdx.x;

    __builtin_amdgcn_fence(__ATOMIC_ACQUIRE, "agent");

    if (tid == 0) {
        u32 xcc = 0;
        asm volatile("s_getreg_b32 %0, hwreg(HW_REG_XCC_ID)" : "=s"(xcc));
        const int my_xcd = (int)(xcc & 7u);
        const int slot = __hip_atomic_fetch_add(&flags[my_xcd], 1, __ATOMIC_ACQ_REL,
                                                __HIP_MEMORY_SCOPE_AGENT);
        __hip_atomic_fetch_add(&flags[15], 1, __ATOMIC_ACQ_REL,
                               __HIP_MEMORY_SCOPE_AGENT);
        int guard = 0;
        while (__hip_atomic_load(&flags[15], __ATOMIC_ACQUIRE,
                                 __HIP_MEMORY_SCOPE_AGENT) < NBLK) {
            if (++guard > GUARD) break;
            __builtin_amdgcn_s_sleep(1);
        }
        int G = 0, pre = 0, myg = 0;
        for (int x = 0; x < 8; ++x) {
            int c  = agent_load(&flags[x]);
            int gx = c / PWG;
            if (x < my_xcd) pre += gx;
            if (x == my_xcd) myg = gx;
            G += gx;
        }
        const int grp = pre + slot / PWG;
        const bool act = (slot < myg * PWG) && (grp < NGRP);
        sh_mode = (G >= NGRP) ? (act ? 1 : 2) : 0;
        sh_g = grp;
        sh_s = slot % PWG;
    }
    __syncthreads();
    const int mode = sh_mode;

    if (mode == 1) {
        // claim-verified single-XCD group -> fast protocol (atomic L2 polls)
        recur_core<true>(sh_g, sh_s, tid, xz, Wh, bh, hsx, flags, hzs);
    } else if (mode == 0) {
        // pathological placement: agent protocol, any layout (proven)
        const int bid = blockIdx.x;
        if (bid < NGRP * PWG)
            recur_core<false>(bid / PWG, bid % PWG, tid, xz, Wh, bh, hsx,
                              flags, hzs);
    }
    // mode == 2: surplus WG, idle
}

// ---------------------------------------------------------------------------
extern "C" void kernel_launch(void* const* d_in, const int* in_sizes, int n_in,
                              void* d_out, int out_size, void* d_ws, size_t ws_size,
                              hipStream_t stream)
{
    const float* x  = (const float*)d_in[0];
    const float* Wx = (const float*)d_in[1];
    const float* bx = (const float*)d_in[2];
    const float* Wh = (const float*)d_in[3];
    const float* bh = (const float*)d_in[4];
    const float* Wp = (const float*)d_in[5];
    float* out = (float*)d_out;

    char* ws = (char*)d_ws;
    size_t off = 0;
    auto wsalloc = [&](size_t bytes) -> void* {
        void* p = ws + off;
        off += (bytes + 255) & ~(size_t)255;
        return p;
    };
    u16* xb   = (u16*)wsalloc(9633792ull * 2);            // x bf16 [12544][768]
    u16* wxb  = (u16*)wsalloc(1769472ull * 2);            // Wx bf16 [2304][768]
    u16* wpb  = (u16*)wsalloc(589824ull * 2);             // Wp bf16 [768][768]
    u16* xzrn = (u16*)wsalloc(196ull * 64 * 2304 * 2);    // [n][b][3C] bf16
    u16* hsx  = (u16*)wsalloc(196ull * 64 * 768 * 2);     // [n][b][C] bf16
    int* flags = (int*)wsalloc(32768);                    // 8192 ints

    // 1) converts (+ zero all flag zones)
    cvt_kernel<<<11712, 256, 0, stream>>>(
        (const float4*)x, (const float4*)Wx, (const float4*)Wp,
        (u32*)xb, (u32*)wxb, (u32*)wpb, flags);

    // 2) x_zrn = seq @ Wx^T + bx  ->  [n][b][3C] bf16
    gemm_bt<1><<<dim3(18, 98), 256, 0, stream>>>(xb, wxb, bx, (void*)xzrn);

    // 3) cooperative batch-split recurrence (claimed XCD-local groups,
    //    atomic-L2 flag polling)
    {
        const u16* a0 = xzrn; const float* a1 = Wh; const float* a2 = bh;
        u16* a3 = hsx; int* a4 = flags;
        void* args[5] = { &a0, &a1, &a2, &a3, &a4 };
        hipLaunchCooperativeKernel((void*)recur4_kernel, dim3(NBLK), dim3(384),
                                   args, 0, stream);
    }

    // 4) y = hsx @ Wp^T -> d_out fp32 (rows m = n*64+b, remapped on store)
    gemm_bt<0><<<dim3(6, 98), 256, 0, stream>>>(hsx, wpb, nullptr, (void*)out);
}